// Round 3
// baseline (1608.850 us; speedup 1.0000x reference)
//
#include <hip/hip_runtime.h>

typedef __bf16 bf16;
typedef __bf16 bf16x4 __attribute__((ext_vector_type(4)));
typedef __bf16 bf16x8 __attribute__((ext_vector_type(8)));
typedef float  f32x4  __attribute__((ext_vector_type(4)));

static constexpr int kC   = 1024;
static constexpr int kT   = 1024;
static constexpr int kB   = 4;
static constexpr int kH   = 16;
static constexpr int kHD  = 64;
static constexpr int kL   = 4;
static constexpr int kFF  = 100;
static constexpr int kFFP = 128;
static constexpr int kM   = kB * kT;

// async global->LDS, 16B per lane; LDS dest must be wave-uniform (HW adds lane*16)
__device__ __forceinline__ void gload16(const bf16* g, bf16* l)
{
    __builtin_amdgcn_global_load_lds(
        (const __attribute__((address_space(1))) void*)g,
        (__attribute__((address_space(3))) void*)l, 16, 0, 0);
}

// ---------------------------------------------------------------------------
__global__ __launch_bounds__(256)
void trans_cvt(const float* __restrict__ src, long sStride,
               bf16* __restrict__ dst, long dStride,
               int K, int N, int KP, int NP)
{
    __shared__ float tile[32][33];
    const int z = blockIdx.z;
    src += (long)z * sStride;
    dst += (long)z * dStride;
    const int n0 = blockIdx.x * 32, k0 = blockIdx.y * 32;
    const int tx = threadIdx.x & 31, ty = threadIdx.x >> 5;
#pragma unroll
    for (int i = 0; i < 4; ++i) {
        int k = k0 + ty + i * 8, n = n0 + tx;
        tile[ty + i * 8][tx] = (k < K && n < N) ? src[(long)k * N + n] : 0.f;
    }
    __syncthreads();
#pragma unroll
    for (int i = 0; i < 4; ++i) {
        int n = n0 + ty + i * 8, k = k0 + tx;
        if (n < NP && k < KP) dst[(long)n * KP + k] = (bf16)tile[tx][ty + i * 8];
    }
}

__global__ __launch_bounds__(256)
void pack_bias(const float* __restrict__ bq, const float* __restrict__ bk,
               const float* __restrict__ bv, float* __restrict__ dst)
{
    int gid = blockIdx.x * 256 + threadIdx.x;
    int l = gid / (3 * kC), w = (gid / kC) % 3, c = gid & (kC - 1);
    const float* s = (w == 0) ? bq : (w == 1) ? bk : bv;
    dst[gid] = s[l * kC + c];
}

__global__ __launch_bounds__(256)
void zero_kernel(float* __restrict__ p, int n)
{
    int i = blockIdx.x * 256 + threadIdx.x;
    if (i < n) p[i] = 0.f;
}

__global__ __launch_bounds__(256)
void embed_kernel(const int* __restrict__ idx, const float* __restrict__ tok,
                  const float* __restrict__ pos, float* __restrict__ x)
{
    const int m = blockIdx.x;
    const int c = threadIdx.x * 4;
    const int t = m & (kT - 1);
    const long tk = (long)idx[m] * kC;
    float4 a = *(const float4*)&tok[tk + c];
    float4 b = *(const float4*)&pos[(long)t * kC + c];
    float4 o; o.x = a.x + b.x; o.y = a.y + b.y; o.z = a.z + b.z; o.w = a.w + b.w;
    *(float4*)&x[(long)m * kC + c] = o;
}

__global__ __launch_bounds__(256)
void ln_kernel(const float* __restrict__ x, const float* __restrict__ g,
               const float* __restrict__ be, bf16* __restrict__ ob,
               float* __restrict__ of, int outf32)
{
    __shared__ float red[8];
    const long row = blockIdx.x;
    const int tid = threadIdx.x, lane = tid & 63, wv = tid >> 6;
    const float4 v = *(const float4*)&x[row * kC + tid * 4];
    float s = v.x + v.y + v.z + v.w;
    float s2 = v.x * v.x + v.y * v.y + v.z * v.z + v.w * v.w;
#pragma unroll
    for (int o = 32; o > 0; o >>= 1) { s += __shfl_down(s, o); s2 += __shfl_down(s2, o); }
    if (!lane) { red[wv] = s; red[4 + wv] = s2; }
    __syncthreads();
    s  = red[0] + red[1] + red[2] + red[3];
    s2 = red[4] + red[5] + red[6] + red[7];
    const float mean = s * (1.f / kC);
    const float var  = s2 * (1.f / kC) - mean * mean;
    const float rstd = rsqrtf(var + 1e-5f);
    const float4 gg = *(const float4*)&g[tid * 4];
    const float4 bb = *(const float4*)&be[tid * 4];
    float o0 = (v.x - mean) * rstd * gg.x + bb.x;
    float o1 = (v.y - mean) * rstd * gg.y + bb.y;
    float o2 = (v.z - mean) * rstd * gg.z + bb.z;
    float o3 = (v.w - mean) * rstd * gg.w + bb.w;
    if (outf32) {
        float4 o; o.x = o0; o.y = o1; o.z = o2; o.w = o3;
        *(float4*)&of[row * kC + tid * 4] = o;
    } else {
        bf16x4 o; o[0] = (bf16)o0; o[1] = (bf16)o1; o[2] = (bf16)o2; o[3] = (bf16)o3;
        *(bf16x4*)&ob[row * kC + tid * 4] = o;
    }
}

// ---------------------------------------------------------------------------
// MFMA GEMM: C[M,N] = A[M,K] * B^T[N,K]. GL=1: global_load_lds staging with
// 16B-block XOR swizzle (128x128 tile only). GL=0: reg-staged, padded LDS.
// MODE 0: QKV (z=0 q, z=1 k -> [B,H,T,HD]; z=2 v -> VT [B,H,HD,T])
// MODE 3: out bf16 = relu(acc + bias[gcol<kFF])
// MODE 4: resid[grow*N+gcol] += acc + bias[gcol]
// ---------------------------------------------------------------------------
template<int WAVES_M, int WAVES_N, int AI, int BJ, int MODE, int GL>
__global__ __launch_bounds__(256)
void gemm_bf16(const bf16* __restrict__ Ag, long strideA,
               const bf16* __restrict__ Bg, long strideB,
               const float* __restrict__ bias, int strideBias,
               bf16* __restrict__ outb, long strideOut,
               float* __restrict__ resid,
               int N, int K, int lda, int ldb)
{
    constexpr int BM = WAVES_M * AI * 16;
    constexpr int BN = WAVES_N * BJ * 16;
    constexpr int BK = 64;
    constexpr int LK = GL ? BK : (BK + 8);
    __shared__ __align__(16) bf16 As[BM * LK];
    __shared__ __align__(16) bf16 Bs[BN * LK];
    const int tid = threadIdx.x, lane = tid & 63, wv = tid >> 6;
    const int wm = wv / WAVES_N, wn = wv % WAVES_N;
    const int lr = lane & 15, lg = lane >> 4;
    const int z = blockIdx.z;
    const bf16* A = Ag + (long)z * strideA;
    const bf16* B = Bg + (long)z * strideB;
    const float* bi = bias ? bias + (long)z * strideBias : nullptr;
    const int m0 = blockIdx.y * BM, n0 = blockIdx.x * BN;

    f32x4 acc[AI][BJ];
#pragma unroll
    for (int i = 0; i < AI; ++i)
#pragma unroll
        for (int j = 0; j < BJ; ++j) acc[i][j] = (f32x4){0.f, 0.f, 0.f, 0.f};

    for (int k0 = 0; k0 < K; k0 += BK) {
        if constexpr (GL) {
            static_assert(BM == 128 && BN == 128, "GL path needs 128x128 tile");
            const int srow = wv * 32 + (lane >> 3);
            const int gcb  = (lane & 7) ^ (lane >> 3);
#pragma unroll
            for (int p = 0; p < 4; ++p) {
                gload16(A + (long)(m0 + srow + p * 8) * lda + k0 + gcb * 8,
                        &As[(wv * 32 + p * 8) * BK]);
                gload16(B + (long)(n0 + srow + p * 8) * ldb + k0 + gcb * 8,
                        &Bs[(wv * 32 + p * 8) * BK]);
            }
        } else {
            constexpr int AP = (BM * BK) / (256 * 8);
#pragma unroll
            for (int p = 0; p < AP; ++p) {
                int r = p * 32 + (tid >> 3), c = (tid & 7) * 8;
                *(uint4*)&As[r * LK + c] = *(const uint4*)&A[(long)(m0 + r) * lda + k0 + c];
            }
            constexpr int BP = (BN * BK) / (256 * 8);
#pragma unroll
            for (int p = 0; p < BP; ++p) {
                int r = p * 32 + (tid >> 3), c = (tid & 7) * 8;
                *(uint4*)&Bs[r * LK + c] = *(const uint4*)&B[(long)(n0 + r) * ldb + k0 + c];
            }
        }
        __syncthreads();
#pragma unroll
        for (int kk = 0; kk < 2; ++kk) {
            bf16x8 af[AI], bfv[BJ];
#pragma unroll
            for (int i = 0; i < AI; ++i) {
                const int r = wm * AI * 16 + i * 16 + lr;
                const int c = GL ? (((kk * 4 + lg) ^ (lr & 7)) * 8) : (kk * 32 + lg * 8);
                af[i] = *(const bf16x8*)&As[r * LK + c];
            }
#pragma unroll
            for (int j = 0; j < BJ; ++j) {
                const int r = wn * BJ * 16 + j * 16 + lr;
                const int c = GL ? (((kk * 4 + lg) ^ (lr & 7)) * 8) : (kk * 32 + lg * 8);
                bfv[j] = *(const bf16x8*)&Bs[r * LK + c];
            }
#pragma unroll
            for (int i = 0; i < AI; ++i)
#pragma unroll
                for (int j = 0; j < BJ; ++j)
                    acc[i][j] = __builtin_amdgcn_mfma_f32_16x16x32_bf16(af[i], bfv[j], acc[i][j], 0, 0, 0);
        }
        __syncthreads();
    }

#pragma unroll
    for (int i = 0; i < AI; ++i)
#pragma unroll
        for (int j = 0; j < BJ; ++j)
#pragma unroll
            for (int rr = 0; rr < 4; ++rr) {
                const int grow = m0 + wm * AI * 16 + i * 16 + lg * 4 + rr;
                const int gcol = n0 + wn * BJ * 16 + j * 16 + lr;
                float v = acc[i][j][rr];
                if constexpr (MODE == 0) {
                    v += bi[gcol];
                    const int b = grow >> 10, t = grow & (kT - 1);
                    const int hh = gcol >> 6, hd = gcol & 63;
                    long o = (long)z * strideOut;
                    if (z == 2) o += (((long)b * kH + hh) * kHD + hd) * kT + t;  // VT
                    else        o += (((long)b * kH + hh) * kT + t) * kHD + hd;  // Q/K
                    outb[o] = (bf16)v;
                } else if constexpr (MODE == 3) {
                    v += (gcol < kFF) ? bi[gcol] : 0.f;
                    outb[(long)grow * N + gcol] = (bf16)fmaxf(v, 0.f);
                } else {
                    v += bi[gcol];
                    resid[(long)grow * N + gcol] += v;
                }
            }
}

// ---------------------------------------------------------------------------
// Fused attention: per block (32 q-rows, head h), loop b=0..3.
//   QK^T (full 1024 cols in regs) -> softmax -> P to LDS (swizzled) ->
//   PV from LDS (VT staged in 2 halves) -> y[b]; attm accumulated in regs
//   across b and written once. P never touches HBM.
// LDS: KV union 128 KB (K[1024][64] -> Ps[32][1024]+VTs[64][512]) + Qs 4 KB.
// ---------------------------------------------------------------------------
__global__ __launch_bounds__(512, 2)
void attn_fused(const bf16* __restrict__ Qg, const bf16* __restrict__ Kg,
                const bf16* __restrict__ VTg, bf16* __restrict__ yg,
                float* __restrict__ attm)
{
    __shared__ __align__(16) bf16 KV[kT * kHD];   // 128 KB
    __shared__ __align__(16) bf16 Qs[32 * kHD];   // 4 KB
    __shared__ float redm[32][8];
    __shared__ float reds[32][8];
    bf16* Ps  = KV;              // [32][1024], 16B-block XOR swizzle by row&7
    bf16* VTs = KV + 32 * kT;    // [64][512],  16B-block XOR swizzle by row&7
    const int tid = threadIdx.x, lane = tid & 63, w = tid >> 6;
    const int lr = lane & 15, lg = lane >> 4;
    const int h = blockIdx.y, q0 = blockIdx.x * 32;
    const int srow8 = lane >> 3, gcb = (lane & 7) ^ srow8;
    const int rh = w >> 2, ch = w & 3;   // PV: wave = one 16x16 y tile
    constexpr float scale = 0.125f;      // 1/sqrt(64)

    f32x4 am[2][8];  // attm accumulator, persists across b
#pragma unroll
    for (int i = 0; i < 2; ++i)
#pragma unroll
        for (int j = 0; j < 8; ++j) am[i][j] = (f32x4){0.f, 0.f, 0.f, 0.f};

    for (int b = 0; b < kB; ++b) {
        const long bh = (long)b * kH + h;
        const bf16* Kb = Kg + bh * kT * kHD;
        const bf16* Qb = Qg + (bh * kT + q0) * kHD;
        const bf16* Vb = VTg + bh * (long)kHD * kT;
        if (b) __syncthreads();   // prior-b PV LDS reads done before restage
        // stage K (128 KB) + Q (4 KB); inverse-swizzled global source
#pragma unroll
        for (int p = 0; p < 16; ++p) {
            const int r0 = w * 128 + p * 8;
            gload16(Kb + (long)(r0 + srow8) * kHD + gcb * 8, &KV[r0 * kHD]);
        }
        if (w < 4)
            gload16(Qb + (long)(w * 8 + srow8) * kHD + gcb * 8, &Qs[w * 8 * kHD]);
        __syncthreads();

        bf16x8 af[2][2];
#pragma unroll
        for (int i = 0; i < 2; ++i)
#pragma unroll
            for (int kk = 0; kk < 2; ++kk)
                af[i][kk] = *(const bf16x8*)&Qs[(i * 16 + lr) * kHD + (((kk * 4 + lg) ^ (lr & 7)) * 8)];

        f32x4 acc[2][8];
#pragma unroll
        for (int i = 0; i < 2; ++i)
#pragma unroll
            for (int j = 0; j < 8; ++j) acc[i][j] = (f32x4){0.f, 0.f, 0.f, 0.f};

#pragma unroll
        for (int j = 0; j < 8; ++j) {
            const int n = w * 128 + j * 16 + lr;   // n&7 == lr&7
#pragma unroll
            for (int kk = 0; kk < 2; ++kk) {
                bf16x8 kf = *(const bf16x8*)&KV[n * kHD + (((kk * 4 + lg) ^ (lr & 7)) * 8)];
                acc[0][j] = __builtin_amdgcn_mfma_f32_16x16x32_bf16(af[0][kk], kf, acc[0][j], 0, 0, 0);
                acc[1][j] = __builtin_amdgcn_mfma_f32_16x16x32_bf16(af[1][kk], kf, acc[1][j], 0, 0, 0);
            }
        }

        // row max (this wave's 128 cols -> cross-wave via LDS)
#pragma unroll
        for (int i = 0; i < 2; ++i)
#pragma unroll
            for (int rr = 0; rr < 4; ++rr) {
                float m = acc[i][0][rr];
#pragma unroll
                for (int j = 1; j < 8; ++j) m = fmaxf(m, acc[i][j][rr]);
#pragma unroll
                for (int off = 1; off < 16; off <<= 1) m = fmaxf(m, __shfl_xor(m, off));
                if (lr == 0) redm[i * 16 + lg * 4 + rr][w] = m;
            }
        __syncthreads();
        float fm[2][4];
#pragma unroll
        for (int i = 0; i < 2; ++i)
#pragma unroll
            for (int rr = 0; rr < 4; ++rr) {
                const int row = i * 16 + lg * 4 + rr;
                float4 a = *(const float4*)&redm[row][0];
                float4 c = *(const float4*)&redm[row][4];
                fm[i][rr] = fmaxf(fmaxf(fmaxf(a.x, a.y), fmaxf(a.z, a.w)),
                                  fmaxf(fmaxf(c.x, c.y), fmaxf(c.z, c.w)));
            }
        // exp + row sum
#pragma unroll
        for (int i = 0; i < 2; ++i)
#pragma unroll
            for (int rr = 0; rr < 4; ++rr) {
                float s = 0.f;
#pragma unroll
                for (int j = 0; j < 8; ++j) {
                    float e = __expf((acc[i][j][rr] - fm[i][rr]) * scale);
                    acc[i][j][rr] = e;
                    s += e;
                }
#pragma unroll
                for (int off = 1; off < 16; off <<= 1) s += __shfl_xor(s, off);
                if (lr == 0) reds[i * 16 + lg * 4 + rr][w] = s;
            }
        __syncthreads();   // also guarantees all waves' K LDS reads are done

        float inv[2][4];
#pragma unroll
        for (int i = 0; i < 2; ++i)
#pragma unroll
            for (int rr = 0; rr < 4; ++rr) {
                const int row = i * 16 + lg * 4 + rr;
                float4 a = *(const float4*)&reds[row][0];
                float4 c = *(const float4*)&reds[row][4];
                inv[i][rr] = 1.f / ((a.x + a.y + a.z + a.w) + (c.x + c.y + c.z + c.w));
            }

        // normalized P -> LDS (swizzled) + attm accumulate (fp32)
#pragma unroll
        for (int i = 0; i < 2; ++i)
#pragma unroll
            for (int rr = 0; rr < 4; ++rr) {
                const int row = i * 16 + lg * 4 + rr;
                const float iv = inv[i][rr];
#pragma unroll
                for (int j = 0; j < 8; ++j) {
                    const int col = w * 128 + j * 16 + lr;
                    const float p = acc[i][j][rr] * iv;
                    am[i][j][rr] += p * 0.25f;
                    Ps[row * kT + (((col >> 3) ^ (row & 7)) << 3) + (col & 7)] = (bf16)p;
                }
            }

        // PV: VT staged in 2 halves of 64 KB; wave computes its 16x16 y tile
        f32x4 yacc = (f32x4){0.f, 0.f, 0.f, 0.f};
#pragma unroll
        for (int hf = 0; hf < 2; ++hf) {
#pragma unroll
            for (int p = 0; p < 8; ++p) {
                const int r = w * 8 + p;
                gload16(Vb + (long)r * kT + hf * 512 + (lane ^ (r & 7)) * 8, &VTs[r * 512]);
            }
            __syncthreads();   // VT half + (hf==0) Ps visible
#pragma unroll
            for (int kk = 0; kk < 16; ++kk) {
                const int rowA = rh * 16 + lr;
                const bf16x8 a = *(const bf16x8*)&Ps[rowA * kT + ((((hf * 16 + kk) * 4 + lg) ^ (lr & 7)) << 3)];
                const int rowB = ch * 16 + lr;
                const bf16x8 v = *(const bf16x8*)&VTs[rowB * 512 + (((kk * 4 + lg) ^ (lr & 7)) << 3)];
                yacc = __builtin_amdgcn_mfma_f32_16x16x32_bf16(a, v, yacc, 0, 0, 0);
            }
            if (hf == 0) __syncthreads();   // VTs reads done before half-2 restage
        }
#pragma unroll
        for (int rr = 0; rr < 4; ++rr)
            yg[((long)b * kT + q0 + rh * 16 + lg * 4 + rr) * kC + h * kHD + ch * 16 + lr] = (bf16)yacc[rr];
    }

    // attm write (once)
    float* ap = attm + ((long)h * kT + q0) * kT;
#pragma unroll
    for (int i = 0; i < 2; ++i)
#pragma unroll
        for (int rr = 0; rr < 4; ++rr) {
            const int row = i * 16 + lg * 4 + rr;
#pragma unroll
            for (int j = 0; j < 8; ++j)
                ap[(long)row * kT + w * 128 + j * 16 + lr] = am[i][j][rr];
        }
}

__global__ __launch_bounds__(256)
void pool_kernel(const float* __restrict__ xf, float* __restrict__ pooled)
{
    const int c = blockIdx.x * 256 + threadIdx.x;
    const int b = blockIdx.y;
    const int t0 = blockIdx.z * 128;
    float s = 0.f;
    for (int t = t0; t < t0 + 128; ++t) s += xf[((long)b * kT + t) * kC + c];
    atomicAdd(&pooled[b * kC + c], s * (1.f / kT));
}

// ---------------------------------------------------------------------------
extern "C" void kernel_launch(void* const* d_in, const int* in_sizes, int n_in,
                              void* d_out, int out_size, void* d_ws, size_t ws_size,
                              hipStream_t stream)
{
    const int*   idx  = (const int*)d_in[0];
    const float* tok  = (const float*)d_in[1];
    const float* pos  = (const float*)d_in[2];
    const float* Wq   = (const float*)d_in[3];
    const float* bq   = (const float*)d_in[4];
    const float* Wk   = (const float*)d_in[5];
    const float* bk   = (const float*)d_in[6];
    const float* Wv   = (const float*)d_in[7];
    const float* bv   = (const float*)d_in[8];
    const float* Wo   = (const float*)d_in[9];
    const float* bo   = (const float*)d_in[10];
    const float* ln1w = (const float*)d_in[11];
    const float* ln1b = (const float*)d_in[12];
    const float* ln2w = (const float*)d_in[13];
    const float* ln2b = (const float*)d_in[14];
    const float* W1   = (const float*)d_in[15];
    const float* b1   = (const float*)d_in[16];
    const float* W2   = (const float*)d_in[17];
    const float* b2   = (const float*)d_in[18];
    const float* lnfw = (const float*)d_in[19];
    const float* lnfb = (const float*)d_in[20];

    char* ws = (char*)d_ws;
    long off = 0;
    auto alloc = [&](long bytes) { char* p = ws + off; off += (bytes + 255) & ~255L; return p; };
    bf16*  WQKVT = (bf16*)alloc((long)kL * 3 * kC * kC * 2);
    bf16*  WOT   = (bf16*)alloc((long)kL * kC * kC * 2);
    bf16*  W1T   = (bf16*)alloc((long)kL * kFFP * kC * 2);
    bf16*  W2T   = (bf16*)alloc((long)kL * kC * kFFP * 2);
    float* BQKV  = (float*)alloc((long)kL * 3 * kC * 4);
    float* X     = (float*)alloc((long)kM * kC * 4);
    bf16*  Hbuf  = (bf16*)alloc((long)kM * kC * 2);
    bf16*  QKV   = (bf16*)alloc(3L * kM * kC * 2);
    bf16*  Y     = (bf16*)alloc((long)kM * kC * 2);
    bf16*  F1    = (bf16*)alloc((long)kM * kFFP * 2);
    float* XF    = (float*)alloc((long)kM * kC * 4);

    float* pooled = (float*)d_out;
    float* attm_base = pooled + kB * kC;

    zero_kernel<<<16, 256, 0, stream>>>(pooled, kB * kC);
    dim3 tg(32, 32, kL);
    trans_cvt<<<tg, 256, 0, stream>>>(Wq, (long)kC * kC, WQKVT + 0L * kC * kC, 3L * kC * kC, kC, kC, kC, kC);
    trans_cvt<<<tg, 256, 0, stream>>>(Wk, (long)kC * kC, WQKVT + 1L * kC * kC, 3L * kC * kC, kC, kC, kC, kC);
    trans_cvt<<<tg, 256, 0, stream>>>(Wv, (long)kC * kC, WQKVT + 2L * kC * kC, 3L * kC * kC, kC, kC, kC, kC);
    trans_cvt<<<tg, 256, 0, stream>>>(Wo, (long)kC * kC, WOT, (long)kC * kC, kC, kC, kC, kC);
    trans_cvt<<<dim3(4, 32, kL), 256, 0, stream>>>(W1, (long)kC * kFF, W1T, (long)kFFP * kC, kC, kFF, kC, kFFP);
    trans_cvt<<<dim3(32, 4, kL), 256, 0, stream>>>(W2, (long)kFF * kC, W2T, (long)kC * kFFP, kFF, kC, kFFP, kC);
    pack_bias<<<48, 256, 0, stream>>>(bq, bk, bv, BQKV);

    embed_kernel<<<kM, 256, 0, stream>>>(idx, tok, pos, X);

    for (int l = 0; l < kL; ++l) {
        ln_kernel<<<kM, 256, 0, stream>>>(X, ln1w + l * kC, ln1b + l * kC, Hbuf, nullptr, 0);
        gemm_bf16<2, 2, 4, 4, 0, 1><<<dim3(8, 32, 3), 256, 0, stream>>>(
            Hbuf, 0L, WQKVT + (long)l * 3 * kC * kC, (long)kC * kC,
            BQKV + l * 3 * kC, kC, QKV, (long)kM * kC, nullptr,
            kC, kC, kC, kC);
        attn_fused<<<dim3(kT / 32, kH), 512, 0, stream>>>(
            QKV, QKV + (long)kM * kC, QKV + 2L * kM * kC, Y,
            attm_base + (long)l * kH * kT * kT);
        gemm_bf16<2, 2, 4, 4, 4, 1><<<dim3(8, 32, 1), 256, 0, stream>>>(
            Y, 0L, WOT + (long)l * kC * kC, 0L, bo + l * kC, 0,
            nullptr, 0L, X, kC, kC, kC, kC);
        ln_kernel<<<kM, 256, 0, stream>>>(X, ln2w + l * kC, ln2b + l * kC, Hbuf, nullptr, 0);
        gemm_bf16<2, 2, 1, 2, 3, 0><<<dim3(2, 128, 1), 256, 0, stream>>>(
            Hbuf, 0L, W1T + (long)l * kFFP * kC, 0L, b1 + l * kFF, 0,
            F1, 0L, nullptr, kFFP, kC, kC, kC);
        gemm_bf16<2, 2, 4, 4, 4, 1><<<dim3(8, 32, 1), 256, 0, stream>>>(
            F1, 0L, W2T + (long)l * kC * kFFP, 0L, b2 + l * kC, 0,
            nullptr, 0L, X, kC, kFFP, kFFP, kFFP);
    }
    ln_kernel<<<kM, 256, 0, stream>>>(X, lnfw, lnfb, nullptr, XF, 1);
    pool_kernel<<<dim3(4, kB, 8), 256, 0, stream>>>(XF, pooled);
}

// Round 4
// 1568.066 us; speedup vs baseline: 1.0260x; 1.0260x over previous
//
#include <hip/hip_runtime.h>

typedef __bf16 bf16;
typedef __bf16 bf16x4 __attribute__((ext_vector_type(4)));
typedef __bf16 bf16x8 __attribute__((ext_vector_type(8)));
typedef float  f32x4  __attribute__((ext_vector_type(4)));

static constexpr int kC   = 1024;
static constexpr int kT   = 1024;
static constexpr int kB   = 4;
static constexpr int kH   = 16;
static constexpr int kHD  = 64;
static constexpr int kL   = 4;
static constexpr int kFF  = 100;
static constexpr int kFFP = 128;
static constexpr int kM   = kB * kT;

// async global->LDS, 16B per lane; LDS dest must be wave-uniform (HW adds lane*16)
__device__ __forceinline__ void gload16(const bf16* g, bf16* l)
{
    __builtin_amdgcn_global_load_lds(
        (const __attribute__((address_space(1))) void*)g,
        (__attribute__((address_space(3))) void*)l, 16, 0, 0);
}

// ---------------------------------------------------------------------------
__global__ __launch_bounds__(256)
void trans_cvt(const float* __restrict__ src, long sStride,
               bf16* __restrict__ dst, long dStride,
               int K, int N, int KP, int NP)
{
    __shared__ float tile[32][33];
    const int z = blockIdx.z;
    src += (long)z * sStride;
    dst += (long)z * dStride;
    const int n0 = blockIdx.x * 32, k0 = blockIdx.y * 32;
    const int tx = threadIdx.x & 31, ty = threadIdx.x >> 5;
#pragma unroll
    for (int i = 0; i < 4; ++i) {
        int k = k0 + ty + i * 8, n = n0 + tx;
        tile[ty + i * 8][tx] = (k < K && n < N) ? src[(long)k * N + n] : 0.f;
    }
    __syncthreads();
#pragma unroll
    for (int i = 0; i < 4; ++i) {
        int n = n0 + ty + i * 8, k = k0 + tx;
        if (n < NP && k < KP) dst[(long)n * KP + k] = (bf16)tile[tx][ty + i * 8];
    }
}

__global__ __launch_bounds__(256)
void pack_bias(const float* __restrict__ bq, const float* __restrict__ bk,
               const float* __restrict__ bv, float* __restrict__ dst)
{
    int gid = blockIdx.x * 256 + threadIdx.x;
    int l = gid / (3 * kC), w = (gid / kC) % 3, c = gid & (kC - 1);
    const float* s = (w == 0) ? bq : (w == 1) ? bk : bv;
    dst[gid] = s[l * kC + c];
}

__global__ __launch_bounds__(256)
void zero_kernel(float* __restrict__ p, int n)
{
    int i = blockIdx.x * 256 + threadIdx.x;
    if (i < n) p[i] = 0.f;
}

__global__ __launch_bounds__(256)
void embed_kernel(const int* __restrict__ idx, const float* __restrict__ tok,
                  const float* __restrict__ pos, float* __restrict__ x)
{
    const int m = blockIdx.x;
    const int c = threadIdx.x * 4;
    const int t = m & (kT - 1);
    const long tk = (long)idx[m] * kC;
    float4 a = *(const float4*)&tok[tk + c];
    float4 b = *(const float4*)&pos[(long)t * kC + c];
    float4 o; o.x = a.x + b.x; o.y = a.y + b.y; o.z = a.z + b.z; o.w = a.w + b.w;
    *(float4*)&x[(long)m * kC + c] = o;
}

__global__ __launch_bounds__(256)
void ln_kernel(const float* __restrict__ x, const float* __restrict__ g,
               const float* __restrict__ be, bf16* __restrict__ ob,
               float* __restrict__ of, int outf32)
{
    __shared__ float red[8];
    const long row = blockIdx.x;
    const int tid = threadIdx.x, lane = tid & 63, wv = tid >> 6;
    const float4 v = *(const float4*)&x[row * kC + tid * 4];
    float s = v.x + v.y + v.z + v.w;
    float s2 = v.x * v.x + v.y * v.y + v.z * v.z + v.w * v.w;
#pragma unroll
    for (int o = 32; o > 0; o >>= 1) { s += __shfl_down(s, o); s2 += __shfl_down(s2, o); }
    if (!lane) { red[wv] = s; red[4 + wv] = s2; }
    __syncthreads();
    s  = red[0] + red[1] + red[2] + red[3];
    s2 = red[4] + red[5] + red[6] + red[7];
    const float mean = s * (1.f / kC);
    const float var  = s2 * (1.f / kC) - mean * mean;
    const float rstd = rsqrtf(var + 1e-5f);
    const float4 gg = *(const float4*)&g[tid * 4];
    const float4 bb = *(const float4*)&be[tid * 4];
    float o0 = (v.x - mean) * rstd * gg.x + bb.x;
    float o1 = (v.y - mean) * rstd * gg.y + bb.y;
    float o2 = (v.z - mean) * rstd * gg.z + bb.z;
    float o3 = (v.w - mean) * rstd * gg.w + bb.w;
    if (outf32) {
        float4 o; o.x = o0; o.y = o1; o.z = o2; o.w = o3;
        *(float4*)&of[row * kC + tid * 4] = o;
    } else {
        bf16x4 o; o[0] = (bf16)o0; o[1] = (bf16)o1; o[2] = (bf16)o2; o[3] = (bf16)o3;
        *(bf16x4*)&ob[row * kC + tid * 4] = o;
    }
}

// ---------------------------------------------------------------------------
// MFMA GEMM: C[M,N] = A[M,K] * B^T[N,K]. GL=1: global_load_lds staging with
// 16B-block XOR swizzle (128x128 tile only). GL=0: reg-staged, padded LDS.
// MODE 0: QKV (z=0 q, z=1 k -> [B,H,T,HD]; z=2 v -> VT [B,H,HD,T])
// MODE 3: out bf16 = relu(acc + bias[gcol<kFF])
// MODE 4: resid[grow*N+gcol] += acc + bias[gcol]
// ---------------------------------------------------------------------------
template<int WAVES_M, int WAVES_N, int AI, int BJ, int MODE, int GL>
__global__ __launch_bounds__(256)
void gemm_bf16(const bf16* __restrict__ Ag, long strideA,
               const bf16* __restrict__ Bg, long strideB,
               const float* __restrict__ bias, int strideBias,
               bf16* __restrict__ outb, long strideOut,
               float* __restrict__ resid,
               int N, int K, int lda, int ldb)
{
    constexpr int BM = WAVES_M * AI * 16;
    constexpr int BN = WAVES_N * BJ * 16;
    constexpr int BK = 64;
    constexpr int LK = GL ? BK : (BK + 8);
    __shared__ __align__(16) bf16 As[BM * LK];
    __shared__ __align__(16) bf16 Bs[BN * LK];
    const int tid = threadIdx.x, lane = tid & 63, wv = tid >> 6;
    const int wm = wv / WAVES_N, wn = wv % WAVES_N;
    const int lr = lane & 15, lg = lane >> 4;
    const int z = blockIdx.z;
    const bf16* A = Ag + (long)z * strideA;
    const bf16* B = Bg + (long)z * strideB;
    const float* bi = bias ? bias + (long)z * strideBias : nullptr;
    const int m0 = blockIdx.y * BM, n0 = blockIdx.x * BN;

    f32x4 acc[AI][BJ];
#pragma unroll
    for (int i = 0; i < AI; ++i)
#pragma unroll
        for (int j = 0; j < BJ; ++j) acc[i][j] = (f32x4){0.f, 0.f, 0.f, 0.f};

    for (int k0 = 0; k0 < K; k0 += BK) {
        if constexpr (GL) {
            static_assert(BM == 128 && BN == 128, "GL path needs 128x128 tile");
            const int srow = wv * 32 + (lane >> 3);
            const int gcb  = (lane & 7) ^ (lane >> 3);
#pragma unroll
            for (int p = 0; p < 4; ++p) {
                gload16(A + (long)(m0 + srow + p * 8) * lda + k0 + gcb * 8,
                        &As[(wv * 32 + p * 8) * BK]);
                gload16(B + (long)(n0 + srow + p * 8) * ldb + k0 + gcb * 8,
                        &Bs[(wv * 32 + p * 8) * BK]);
            }
        } else {
            constexpr int AP = (BM * BK) / (256 * 8);
#pragma unroll
            for (int p = 0; p < AP; ++p) {
                int r = p * 32 + (tid >> 3), c = (tid & 7) * 8;
                *(uint4*)&As[r * LK + c] = *(const uint4*)&A[(long)(m0 + r) * lda + k0 + c];
            }
            constexpr int BP = (BN * BK) / (256 * 8);
#pragma unroll
            for (int p = 0; p < BP; ++p) {
                int r = p * 32 + (tid >> 3), c = (tid & 7) * 8;
                *(uint4*)&Bs[r * LK + c] = *(const uint4*)&B[(long)(n0 + r) * ldb + k0 + c];
            }
        }
        __syncthreads();
#pragma unroll
        for (int kk = 0; kk < 2; ++kk) {
            bf16x8 af[AI], bfv[BJ];
#pragma unroll
            for (int i = 0; i < AI; ++i) {
                const int r = wm * AI * 16 + i * 16 + lr;
                const int c = GL ? (((kk * 4 + lg) ^ (lr & 7)) * 8) : (kk * 32 + lg * 8);
                af[i] = *(const bf16x8*)&As[r * LK + c];
            }
#pragma unroll
            for (int j = 0; j < BJ; ++j) {
                const int r = wn * BJ * 16 + j * 16 + lr;
                const int c = GL ? (((kk * 4 + lg) ^ (lr & 7)) * 8) : (kk * 32 + lg * 8);
                bfv[j] = *(const bf16x8*)&Bs[r * LK + c];
            }
#pragma unroll
            for (int i = 0; i < AI; ++i)
#pragma unroll
                for (int j = 0; j < BJ; ++j)
                    acc[i][j] = __builtin_amdgcn_mfma_f32_16x16x32_bf16(af[i], bfv[j], acc[i][j], 0, 0, 0);
        }
        __syncthreads();
    }

#pragma unroll
    for (int i = 0; i < AI; ++i)
#pragma unroll
        for (int j = 0; j < BJ; ++j)
#pragma unroll
            for (int rr = 0; rr < 4; ++rr) {
                const int grow = m0 + wm * AI * 16 + i * 16 + lg * 4 + rr;
                const int gcol = n0 + wn * BJ * 16 + j * 16 + lr;
                float v = acc[i][j][rr];
                if constexpr (MODE == 0) {
                    v += bi[gcol];
                    const int b = grow >> 10, t = grow & (kT - 1);
                    const int hh = gcol >> 6, hd = gcol & 63;
                    long o = (long)z * strideOut;
                    if (z == 2) o += (((long)b * kH + hh) * kHD + hd) * kT + t;  // VT
                    else        o += (((long)b * kH + hh) * kT + t) * kHD + hd;  // Q/K
                    outb[o] = (bf16)v;
                } else if constexpr (MODE == 3) {
                    v += (gcol < kFF) ? bi[gcol] : 0.f;
                    outb[(long)grow * N + gcol] = (bf16)fmaxf(v, 0.f);
                } else {
                    v += bi[gcol];
                    resid[(long)grow * N + gcol] += v;
                }
            }
}

// ---------------------------------------------------------------------------
// Fused attention v3. Block = (32 q-rows, head h), XCD-decoded so both
// blocks-sharing-h land on one XCD (K/V become L2-resident). Loop b=0..3:
// stage K full -> QK^T -> softmax (VT q0 stage issued under P-normalize) ->
// P to LDS -> PV over 4 double-buffered 32KB VT quarters. attm in regs.
// LDS: KV 128 KB (K[1024][64] -> Ps[32][1024] + VTq 2x32KB) + Qs 4 KB.
// ---------------------------------------------------------------------------
__global__ __launch_bounds__(512, 1)
void attn_fused(const bf16* __restrict__ Qg, const bf16* __restrict__ Kg,
                const bf16* __restrict__ VTg, bf16* __restrict__ yg,
                float* __restrict__ attm)
{
    __shared__ __align__(16) bf16 KV[kT * kHD];   // 128 KB
    __shared__ __align__(16) bf16 Qs[32 * kHD];   // 4 KB
    __shared__ float redm[32][8];
    __shared__ float reds[32][8];
    bf16* Ps = KV;                                // [32][1024] swizzled, 64 KB
    bf16* VTq = KV + 32 * kT;                     // 2 x [64][256] quarters, 64 KB
    const int tid = threadIdx.x, lane = tid & 63, w = tid >> 6;
    const int lr = lane & 15, lg = lane >> 4;
    // XCD-aware decode: bid%8 = XCD (round-robin); h = 2*xcd + parity
    const int bid = blockIdx.x;                   // 0..511
    const int r_ = bid >> 3;
    const int h = ((bid & 7) << 1) | (r_ & 1);
    const int q0 = (r_ >> 1) * 32;
    const int srow8 = lane >> 3, gcb = (lane & 7) ^ srow8;
    const int rh = w >> 2, ch = w & 3;            // PV: wave = one 16x16 y tile
    constexpr float scale = 0.125f;               // 1/sqrt(64)

    f32x4 am[2][8];                               // attm accumulator across b
#pragma unroll
    for (int i = 0; i < 2; ++i)
#pragma unroll
        for (int j = 0; j < 8; ++j) am[i][j] = (f32x4){0.f, 0.f, 0.f, 0.f};

    for (int b = 0; b < kB; ++b) {
        const long bh = (long)b * kH + h;
        const bf16* Kb = Kg + bh * kT * kHD;
        const bf16* Qb = Qg + (bh * kT + q0) * kHD;
        const bf16* Vb = VTg + bh * (long)kHD * kT;

        // stage K (128 KB) + Q (4 KB); inverse-swizzled global source
#pragma unroll
        for (int p = 0; p < 16; ++p) {
            const int r0 = w * 128 + p * 8;
            gload16(Kb + (long)(r0 + srow8) * kHD + gcb * 8, &KV[r0 * kHD]);
        }
        if (w < 4)
            gload16(Qb + (long)(w * 8 + srow8) * kHD + gcb * 8, &Qs[w * 8 * kHD]);
        __syncthreads();

        bf16x8 af[2][2];
#pragma unroll
        for (int i = 0; i < 2; ++i)
#pragma unroll
            for (int kk = 0; kk < 2; ++kk)
                af[i][kk] = *(const bf16x8*)&Qs[(i * 16 + lr) * kHD + (((kk * 4 + lg) ^ (lr & 7)) * 8)];

        f32x4 acc[2][8];
#pragma unroll
        for (int i = 0; i < 2; ++i)
#pragma unroll
            for (int j = 0; j < 8; ++j) acc[i][j] = (f32x4){0.f, 0.f, 0.f, 0.f};

#pragma unroll
        for (int j = 0; j < 8; ++j) {
            const int n = w * 128 + j * 16 + lr;   // n&7 == lr&7
#pragma unroll
            for (int kk = 0; kk < 2; ++kk) {
                bf16x8 kf = *(const bf16x8*)&KV[n * kHD + (((kk * 4 + lg) ^ (lr & 7)) * 8)];
                acc[0][j] = __builtin_amdgcn_mfma_f32_16x16x32_bf16(af[0][kk], kf, acc[0][j], 0, 0, 0);
                acc[1][j] = __builtin_amdgcn_mfma_f32_16x16x32_bf16(af[1][kk], kf, acc[1][j], 0, 0, 0);
            }
        }

        // row max (wave's 128 cols -> cross-wave via LDS)
#pragma unroll
        for (int i = 0; i < 2; ++i)
#pragma unroll
            for (int rr = 0; rr < 4; ++rr) {
                float m = acc[i][0][rr];
#pragma unroll
                for (int j = 1; j < 8; ++j) m = fmaxf(m, acc[i][j][rr]);
#pragma unroll
                for (int off = 1; off < 16; off <<= 1) m = fmaxf(m, __shfl_xor(m, off));
                if (lr == 0) redm[i * 16 + lg * 4 + rr][w] = m;
            }
        __syncthreads();   // all K LDS reads complete beyond this point
        float fm[2][4];
#pragma unroll
        for (int i = 0; i < 2; ++i)
#pragma unroll
            for (int rr = 0; rr < 4; ++rr) {
                const int row = i * 16 + lg * 4 + rr;
                float4 a = *(const float4*)&redm[row][0];
                float4 c = *(const float4*)&redm[row][4];
                fm[i][rr] = fmaxf(fmaxf(fmaxf(a.x, a.y), fmaxf(a.z, a.w)),
                                  fmaxf(fmaxf(c.x, c.y), fmaxf(c.z, c.w)));
            }
        // exp + row sum
#pragma unroll
        for (int i = 0; i < 2; ++i)
#pragma unroll
            for (int rr = 0; rr < 4; ++rr) {
                float s = 0.f;
#pragma unroll
                for (int j = 0; j < 8; ++j) {
                    float e = __expf((acc[i][j][rr] - fm[i][rr]) * scale);
                    acc[i][j][rr] = e;
                    s += e;
                }
#pragma unroll
                for (int off = 1; off < 16; off <<= 1) s += __shfl_xor(s, off);
                if (lr == 0) reds[i * 16 + lg * 4 + rr][w] = s;
            }
        __syncthreads();

        // issue VT quarter-0 stage now (K region dead; overlaps P-write VALU)
        {
            const int row = w * 8 + (lane >> 5);      // per gload: 2 rows
#pragma unroll
            for (int g = 0; g < 4; ++g) {
                const int rw = row + g * 2;
                gload16(Vb + (long)rw * kT + ((lane & 31) ^ (rw & 7)) * 8,
                        &VTq[(w * 8 + g * 2) * 256]);
            }
        }

        float inv[2][4];
#pragma unroll
        for (int i = 0; i < 2; ++i)
#pragma unroll
            for (int rr = 0; rr < 4; ++rr) {
                const int row = i * 16 + lg * 4 + rr;
                float4 a = *(const float4*)&reds[row][0];
                float4 c = *(const float4*)&reds[row][4];
                inv[i][rr] = 1.f / ((a.x + a.y + a.z + a.w) + (c.x + c.y + c.z + c.w));
            }

        // normalized P -> LDS (16B-block XOR swizzle) + attm accumulate
#pragma unroll
        for (int i = 0; i < 2; ++i)
#pragma unroll
            for (int rr = 0; rr < 4; ++rr) {
                const int row = i * 16 + lg * 4 + rr;
                const float iv = inv[i][rr];
#pragma unroll
                for (int j = 0; j < 8; ++j) {
                    const int col = w * 128 + j * 16 + lr;
                    const float p = acc[i][j][rr] * iv;
                    am[i][j][rr] += p * 0.25f;
                    Ps[row * kT + (((col >> 3) ^ (row & 7)) << 3) + (col & 7)] = (bf16)p;
                }
            }
        __syncthreads();   // Ps visible + VT quarter-0 arrived (vmcnt drain)

        // PV over 4 quarters, double-buffered 32KB VT tiles
        f32x4 yacc = (f32x4){0.f, 0.f, 0.f, 0.f};
        for (int qtr = 0; qtr < 4; ++qtr) {
            if (qtr < 3) {
                bf16* dstb = VTq + ((qtr + 1) & 1) * (64 * 256);
                const int row = w * 8 + (lane >> 5);
#pragma unroll
                for (int g = 0; g < 4; ++g) {
                    const int rw = row + g * 2;
                    gload16(Vb + (long)rw * kT + (qtr + 1) * 256 + ((lane & 31) ^ (rw & 7)) * 8,
                            &dstb[(w * 8 + g * 2) * 256]);
                }
            }
            const bf16* curb = VTq + (qtr & 1) * (64 * 256);
            const int rowA = rh * 16 + lr;
            const int rowB = ch * 16 + lr;
#pragma unroll
            for (int kk = 0; kk < 8; ++kk) {
                const bf16x8 a = *(const bf16x8*)&Ps[rowA * kT + (((qtr * 32 + kk * 4 + lg) ^ (lr & 7)) << 3)];
                const bf16x8 v = *(const bf16x8*)&curb[rowB * 256 + (((kk * 4 + lg) ^ (lr & 7)) << 3)];
                yacc = __builtin_amdgcn_mfma_f32_16x16x32_bf16(a, v, yacc, 0, 0, 0);
            }
            __syncthreads();   // next VT buf ready; reads of cur buf done
        }
#pragma unroll
        for (int rr = 0; rr < 4; ++rr)
            yg[((long)b * kT + q0 + rh * 16 + lg * 4 + rr) * kC + h * kHD + ch * 16 + lr] = (bf16)yacc[rr];
        // loop-final barrier above also frees Ps/K region for next b
    }

    // attm write (once)
    float* ap = attm + ((long)h * kT + q0) * kT;
#pragma unroll
    for (int i = 0; i < 2; ++i)
#pragma unroll
        for (int rr = 0; rr < 4; ++rr) {
            const int row = i * 16 + lg * 4 + rr;
#pragma unroll
            for (int j = 0; j < 8; ++j)
                ap[(long)row * kT + w * 128 + j * 16 + lr] = am[i][j][rr];
        }
}

__global__ __launch_bounds__(256)
void pool_kernel(const float* __restrict__ xf, float* __restrict__ pooled)
{
    const int c = blockIdx.x * 256 + threadIdx.x;
    const int b = blockIdx.y;
    const int t0 = blockIdx.z * 128;
    float s = 0.f;
    for (int t = t0; t < t0 + 128; ++t) s += xf[((long)b * kT + t) * kC + c];
    atomicAdd(&pooled[b * kC + c], s * (1.f / kT));
}

// ---------------------------------------------------------------------------
extern "C" void kernel_launch(void* const* d_in, const int* in_sizes, int n_in,
                              void* d_out, int out_size, void* d_ws, size_t ws_size,
                              hipStream_t stream)
{
    const int*   idx  = (const int*)d_in[0];
    const float* tok  = (const float*)d_in[1];
    const float* pos  = (const float*)d_in[2];
    const float* Wq   = (const float*)d_in[3];
    const float* bq   = (const float*)d_in[4];
    const float* Wk   = (const float*)d_in[5];
    const float* bk   = (const float*)d_in[6];
    const float* Wv   = (const float*)d_in[7];
    const float* bv   = (const float*)d_in[8];
    const float* Wo   = (const float*)d_in[9];
    const float* bo   = (const float*)d_in[10];
    const float* ln1w = (const float*)d_in[11];
    const float* ln1b = (const float*)d_in[12];
    const float* ln2w = (const float*)d_in[13];
    const float* ln2b = (const float*)d_in[14];
    const float* W1   = (const float*)d_in[15];
    const float* b1   = (const float*)d_in[16];
    const float* W2   = (const float*)d_in[17];
    const float* b2   = (const float*)d_in[18];
    const float* lnfw = (const float*)d_in[19];
    const float* lnfb = (const float*)d_in[20];

    char* ws = (char*)d_ws;
    long off = 0;
    auto alloc = [&](long bytes) { char* p = ws + off; off += (bytes + 255) & ~255L; return p; };
    bf16*  WQKVT = (bf16*)alloc((long)kL * 3 * kC * kC * 2);
    bf16*  WOT   = (bf16*)alloc((long)kL * kC * kC * 2);
    bf16*  W1T   = (bf16*)alloc((long)kL * kFFP * kC * 2);
    bf16*  W2T   = (bf16*)alloc((long)kL * kC * kFFP * 2);
    float* BQKV  = (float*)alloc((long)kL * 3 * kC * 4);
    float* X     = (float*)alloc((long)kM * kC * 4);
    bf16*  Hbuf  = (bf16*)alloc((long)kM * kC * 2);
    bf16*  QKV   = (bf16*)alloc(3L * kM * kC * 2);
    bf16*  Y     = (bf16*)alloc((long)kM * kC * 2);
    bf16*  F1    = (bf16*)alloc((long)kM * kFFP * 2);
    float* XF    = (float*)alloc((long)kM * kC * 4);

    float* pooled = (float*)d_out;
    float* attm_base = pooled + kB * kC;

    zero_kernel<<<16, 256, 0, stream>>>(pooled, kB * kC);
    dim3 tg(32, 32, kL);
    trans_cvt<<<tg, 256, 0, stream>>>(Wq, (long)kC * kC, WQKVT + 0L * kC * kC, 3L * kC * kC, kC, kC, kC, kC);
    trans_cvt<<<tg, 256, 0, stream>>>(Wk, (long)kC * kC, WQKVT + 1L * kC * kC, 3L * kC * kC, kC, kC, kC, kC);
    trans_cvt<<<tg, 256, 0, stream>>>(Wv, (long)kC * kC, WQKVT + 2L * kC * kC, 3L * kC * kC, kC, kC, kC, kC);
    trans_cvt<<<tg, 256, 0, stream>>>(Wo, (long)kC * kC, WOT, (long)kC * kC, kC, kC, kC, kC);
    trans_cvt<<<dim3(4, 32, kL), 256, 0, stream>>>(W1, (long)kC * kFF, W1T, (long)kFFP * kC, kC, kFF, kC, kFFP);
    trans_cvt<<<dim3(32, 4, kL), 256, 0, stream>>>(W2, (long)kFF * kC, W2T, (long)kC * kFFP, kFF, kC, kFFP, kC);
    pack_bias<<<48, 256, 0, stream>>>(bq, bk, bv, BQKV);

    embed_kernel<<<kM, 256, 0, stream>>>(idx, tok, pos, X);

    for (int l = 0; l < kL; ++l) {
        ln_kernel<<<kM, 256, 0, stream>>>(X, ln1w + l * kC, ln1b + l * kC, Hbuf, nullptr, 0);
        gemm_bf16<2, 2, 4, 4, 0, 1><<<dim3(8, 32, 3), 256, 0, stream>>>(
            Hbuf, 0L, WQKVT + (long)l * 3 * kC * kC, (long)kC * kC,
            BQKV + l * 3 * kC, kC, QKV, (long)kM * kC, nullptr,
            kC, kC, kC, kC);
        attn_fused<<<dim3(512), 512, 0, stream>>>(
            QKV, QKV + (long)kM * kC, QKV + 2L * kM * kC, Y,
            attm_base + (long)l * kH * kT * kT);
        gemm_bf16<2, 2, 4, 4, 4, 1><<<dim3(8, 32, 1), 256, 0, stream>>>(
            Y, 0L, WOT + (long)l * kC * kC, 0L, bo + l * kC, 0,
            nullptr, 0L, X, kC, kC, kC, kC);
        ln_kernel<<<kM, 256, 0, stream>>>(X, ln2w + l * kC, ln2b + l * kC, Hbuf, nullptr, 0);
        gemm_bf16<2, 2, 1, 2, 3, 0><<<dim3(2, 128, 1), 256, 0, stream>>>(
            Hbuf, 0L, W1T + (long)l * kFFP * kC, 0L, b1 + l * kFF, 0,
            F1, 0L, nullptr, kFFP, kC, kC, kC);
        gemm_bf16<2, 2, 4, 4, 4, 1><<<dim3(8, 32, 1), 256, 0, stream>>>(
            F1, 0L, W2T + (long)l * kC * kFFP, 0L, b2 + l * kC, 0,
            nullptr, 0L, X, kC, kFFP, kFFP, kFFP);
    }
    ln_kernel<<<kM, 256, 0, stream>>>(X, lnfw, lnfb, nullptr, XF, 1);
    pool_kernel<<<dim3(4, kB, 8), 256, 0, stream>>>(XF, pooled);
}

// Round 5
// 1247.517 us; speedup vs baseline: 1.2896x; 1.2569x over previous
//
#include <hip/hip_runtime.h>

typedef __bf16 bf16;
typedef __bf16 bf16x4 __attribute__((ext_vector_type(4)));
typedef __bf16 bf16x8 __attribute__((ext_vector_type(8)));
typedef float  f32x4  __attribute__((ext_vector_type(4)));

static constexpr int kC   = 1024;
static constexpr int kT   = 1024;
static constexpr int kB   = 4;
static constexpr int kH   = 16;
static constexpr int kHD  = 64;
static constexpr int kL   = 4;
static constexpr int kFF  = 100;
static constexpr int kFFP = 128;
static constexpr int kM   = kB * kT;

// async global->LDS, 16B per lane; LDS dest must be wave-uniform (HW adds lane*16)
__device__ __forceinline__ void gload16(const bf16* g, bf16* l)
{
    __builtin_amdgcn_global_load_lds(
        (const __attribute__((address_space(1))) void*)g,
        (__attribute__((address_space(3))) void*)l, 16, 0, 0);
}

// ---------------------------------------------------------------------------
__global__ __launch_bounds__(256)
void trans_cvt(const float* __restrict__ src, long sStride,
               bf16* __restrict__ dst, long dStride,
               int K, int N, int KP, int NP)
{
    __shared__ float tile[32][33];
    const int z = blockIdx.z;
    src += (long)z * sStride;
    dst += (long)z * dStride;
    const int n0 = blockIdx.x * 32, k0 = blockIdx.y * 32;
    const int tx = threadIdx.x & 31, ty = threadIdx.x >> 5;
#pragma unroll
    for (int i = 0; i < 4; ++i) {
        int k = k0 + ty + i * 8, n = n0 + tx;
        tile[ty + i * 8][tx] = (k < K && n < N) ? src[(long)k * N + n] : 0.f;
    }
    __syncthreads();
#pragma unroll
    for (int i = 0; i < 4; ++i) {
        int n = n0 + ty + i * 8, k = k0 + tx;
        if (n < NP && k < KP) dst[(long)n * KP + k] = (bf16)tile[tx][ty + i * 8];
    }
}

__global__ __launch_bounds__(256)
void pack_bias(const float* __restrict__ bq, const float* __restrict__ bk,
               const float* __restrict__ bv, float* __restrict__ dst)
{
    int gid = blockIdx.x * 256 + threadIdx.x;
    int l = gid / (3 * kC), w = (gid / kC) % 3, c = gid & (kC - 1);
    const float* s = (w == 0) ? bq : (w == 1) ? bk : bv;
    dst[gid] = s[l * kC + c];
}

__global__ __launch_bounds__(256)
void zero_kernel(float* __restrict__ p, int n)
{
    int i = blockIdx.x * 256 + threadIdx.x;
    if (i < n) p[i] = 0.f;
}

__global__ __launch_bounds__(256)
void embed_kernel(const int* __restrict__ idx, const float* __restrict__ tok,
                  const float* __restrict__ pos, float* __restrict__ x)
{
    const int m = blockIdx.x;
    const int c = threadIdx.x * 4;
    const int t = m & (kT - 1);
    const long tk = (long)idx[m] * kC;
    float4 a = *(const float4*)&tok[tk + c];
    float4 b = *(const float4*)&pos[(long)t * kC + c];
    float4 o; o.x = a.x + b.x; o.y = a.y + b.y; o.z = a.z + b.z; o.w = a.w + b.w;
    *(float4*)&x[(long)m * kC + c] = o;
}

__global__ __launch_bounds__(256)
void ln_kernel(const float* __restrict__ x, const float* __restrict__ g,
               const float* __restrict__ be, bf16* __restrict__ ob,
               float* __restrict__ of, int outf32)
{
    __shared__ float red[8];
    const long row = blockIdx.x;
    const int tid = threadIdx.x, lane = tid & 63, wv = tid >> 6;
    const float4 v = *(const float4*)&x[row * kC + tid * 4];
    float s = v.x + v.y + v.z + v.w;
    float s2 = v.x * v.x + v.y * v.y + v.z * v.z + v.w * v.w;
#pragma unroll
    for (int o = 32; o > 0; o >>= 1) { s += __shfl_down(s, o); s2 += __shfl_down(s2, o); }
    if (!lane) { red[wv] = s; red[4 + wv] = s2; }
    __syncthreads();
    s  = red[0] + red[1] + red[2] + red[3];
    s2 = red[4] + red[5] + red[6] + red[7];
    const float mean = s * (1.f / kC);
    const float var  = s2 * (1.f / kC) - mean * mean;
    const float rstd = rsqrtf(var + 1e-5f);
    const float4 gg = *(const float4*)&g[tid * 4];
    const float4 bb = *(const float4*)&be[tid * 4];
    float o0 = (v.x - mean) * rstd * gg.x + bb.x;
    float o1 = (v.y - mean) * rstd * gg.y + bb.y;
    float o2 = (v.z - mean) * rstd * gg.z + bb.z;
    float o3 = (v.w - mean) * rstd * gg.w + bb.w;
    if (outf32) {
        float4 o; o.x = o0; o.y = o1; o.z = o2; o.w = o3;
        *(float4*)&of[row * kC + tid * 4] = o;
    } else {
        bf16x4 o; o[0] = (bf16)o0; o[1] = (bf16)o1; o[2] = (bf16)o2; o[3] = (bf16)o3;
        *(bf16x4*)&ob[row * kC + tid * 4] = o;
    }
}

// ---------------------------------------------------------------------------
// MFMA GEMM: C[M,N] = A[M,K] * B^T[N,K]. GL=1: global_load_lds staging with
// 16B-block XOR swizzle (128x128 tile only). GL=0: reg-staged, padded LDS.
// MODE 0: QKV (z=0 q, z=1 k -> [B,H,T,HD]; z=2 v -> VT [B,H,HD,T])
// MODE 3: out bf16 = relu(acc + bias[gcol<kFF])
// MODE 4: resid[grow*N+gcol] += acc + bias[gcol]
// ---------------------------------------------------------------------------
template<int WAVES_M, int WAVES_N, int AI, int BJ, int MODE, int GL>
__global__ __launch_bounds__(256)
void gemm_bf16(const bf16* __restrict__ Ag, long strideA,
               const bf16* __restrict__ Bg, long strideB,
               const float* __restrict__ bias, int strideBias,
               bf16* __restrict__ outb, long strideOut,
               float* __restrict__ resid,
               int N, int K, int lda, int ldb)
{
    constexpr int BM = WAVES_M * AI * 16;
    constexpr int BN = WAVES_N * BJ * 16;
    constexpr int BK = 64;
    constexpr int LK = GL ? BK : (BK + 8);
    __shared__ __align__(16) bf16 As[BM * LK];
    __shared__ __align__(16) bf16 Bs[BN * LK];
    const int tid = threadIdx.x, lane = tid & 63, wv = tid >> 6;
    const int wm = wv / WAVES_N, wn = wv % WAVES_N;
    const int lr = lane & 15, lg = lane >> 4;
    const int z = blockIdx.z;
    const bf16* A = Ag + (long)z * strideA;
    const bf16* B = Bg + (long)z * strideB;
    const float* bi = bias ? bias + (long)z * strideBias : nullptr;
    const int m0 = blockIdx.y * BM, n0 = blockIdx.x * BN;

    f32x4 acc[AI][BJ];
#pragma unroll
    for (int i = 0; i < AI; ++i)
#pragma unroll
        for (int j = 0; j < BJ; ++j) acc[i][j] = (f32x4){0.f, 0.f, 0.f, 0.f};

    for (int k0 = 0; k0 < K; k0 += BK) {
        if constexpr (GL) {
            static_assert(BM == 128 && BN == 128, "GL path needs 128x128 tile");
            const int srow = wv * 32 + (lane >> 3);
            const int gcb  = (lane & 7) ^ (lane >> 3);
#pragma unroll
            for (int p = 0; p < 4; ++p) {
                gload16(A + (long)(m0 + srow + p * 8) * lda + k0 + gcb * 8,
                        &As[(wv * 32 + p * 8) * BK]);
                gload16(B + (long)(n0 + srow + p * 8) * ldb + k0 + gcb * 8,
                        &Bs[(wv * 32 + p * 8) * BK]);
            }
        } else {
            constexpr int AP = (BM * BK) / (256 * 8);
#pragma unroll
            for (int p = 0; p < AP; ++p) {
                int r = p * 32 + (tid >> 3), c = (tid & 7) * 8;
                *(uint4*)&As[r * LK + c] = *(const uint4*)&A[(long)(m0 + r) * lda + k0 + c];
            }
            constexpr int BP = (BN * BK) / (256 * 8);
#pragma unroll
            for (int p = 0; p < BP; ++p) {
                int r = p * 32 + (tid >> 3), c = (tid & 7) * 8;
                *(uint4*)&Bs[r * LK + c] = *(const uint4*)&B[(long)(n0 + r) * ldb + k0 + c];
            }
        }
        __syncthreads();
#pragma unroll
        for (int kk = 0; kk < 2; ++kk) {
            bf16x8 af[AI], bfv[BJ];
#pragma unroll
            for (int i = 0; i < AI; ++i) {
                const int r = wm * AI * 16 + i * 16 + lr;
                const int c = GL ? (((kk * 4 + lg) ^ (lr & 7)) * 8) : (kk * 32 + lg * 8);
                af[i] = *(const bf16x8*)&As[r * LK + c];
            }
#pragma unroll
            for (int j = 0; j < BJ; ++j) {
                const int r = wn * BJ * 16 + j * 16 + lr;
                const int c = GL ? (((kk * 4 + lg) ^ (lr & 7)) * 8) : (kk * 32 + lg * 8);
                bfv[j] = *(const bf16x8*)&Bs[r * LK + c];
            }
#pragma unroll
            for (int i = 0; i < AI; ++i)
#pragma unroll
                for (int j = 0; j < BJ; ++j)
                    acc[i][j] = __builtin_amdgcn_mfma_f32_16x16x32_bf16(af[i], bfv[j], acc[i][j], 0, 0, 0);
        }
        __syncthreads();
    }

#pragma unroll
    for (int i = 0; i < AI; ++i)
#pragma unroll
        for (int j = 0; j < BJ; ++j)
#pragma unroll
            for (int rr = 0; rr < 4; ++rr) {
                const int grow = m0 + wm * AI * 16 + i * 16 + lg * 4 + rr;
                const int gcol = n0 + wn * BJ * 16 + j * 16 + lr;
                float v = acc[i][j][rr];
                if constexpr (MODE == 0) {
                    v += bi[gcol];
                    const int b = grow >> 10, t = grow & (kT - 1);
                    const int hh = gcol >> 6, hd = gcol & 63;
                    long o = (long)z * strideOut;
                    if (z == 2) o += (((long)b * kH + hh) * kHD + hd) * kT + t;  // VT
                    else        o += (((long)b * kH + hh) * kT + t) * kHD + hd;  // Q/K
                    outb[o] = (bf16)v;
                } else if constexpr (MODE == 3) {
                    v += (gcol < kFF) ? bi[gcol] : 0.f;
                    outb[(long)grow * N + gcol] = (bf16)fmaxf(v, 0.f);
                } else {
                    v += bi[gcol];
                    resid[(long)grow * N + gcol] += v;
                }
            }
}

// ---------------------------------------------------------------------------
// Fused attention v4: NO K/V/Q LDS staging (direct L2 reads — data is
// XCD-L2-resident via the block decode). LDS only holds Ps (P^T buffer for
// PV's A-operand, XOR-swizzled) + softmax reductions. 3 barriers per b.
// attm accumulated in regs across b, written coalesced via LDS at the end.
// Block = (32 q-rows, h), loop b=0..3. Grid 512, 8 waves.
// ---------------------------------------------------------------------------
__global__ __launch_bounds__(512, 1)
void attn_fused(const bf16* __restrict__ Qg, const bf16* __restrict__ Kg,
                const bf16* __restrict__ VTg, bf16* __restrict__ yg,
                float* __restrict__ attm)
{
    __shared__ __align__(16) bf16 Ps[32 * kT];    // 64 KB; reused as fp32 [32][512]
    __shared__ float redm[32][8];
    __shared__ float reds[32][8];
    const int tid = threadIdx.x, lane = tid & 63, w = tid >> 6;
    const int lr = lane & 15, lg = lane >> 4;
    // XCD-aware decode: bid%8 = XCD (round-robin); h = 2*xcd + parity
    const int bid = blockIdx.x, r_ = bid >> 3;
    const int h = ((bid & 7) << 1) | (r_ & 1);
    const int q0 = (r_ >> 1) * 32;
    const int rh = w >> 2, ch = w & 3;            // PV: wave = one 16x16 y tile
    constexpr float scale = 0.125f;               // 1/sqrt(64)

    f32x4 am[2][8];                               // attm accumulator across b
#pragma unroll
    for (int i = 0; i < 2; ++i)
#pragma unroll
        for (int j = 0; j < 8; ++j) am[i][j] = (f32x4){0.f, 0.f, 0.f, 0.f};

    for (int b = 0; b < kB; ++b) {
        const long bh = (long)b * kH + h;
        const bf16* Qb = Qg + (bh * kT + q0) * kHD;
        const bf16* Kb = Kg + bh * kT * kHD;
        const bf16* Vb = VTg + bh * (long)kHD * kT;

        // Q fragments direct from global (all waves read same 4 KB -> L2)
        bf16x8 af[2][2];
#pragma unroll
        for (int i = 0; i < 2; ++i)
#pragma unroll
            for (int kk = 0; kk < 2; ++kk)
                af[i][kk] = *(const bf16x8*)&Qb[(long)(i * 16 + lr) * kHD + kk * 32 + lg * 8];

        // QK^T: wave w owns cols w*128..+127; K fragments direct from L2
        f32x4 acc[2][8];
#pragma unroll
        for (int i = 0; i < 2; ++i)
#pragma unroll
            for (int j = 0; j < 8; ++j) acc[i][j] = (f32x4){0.f, 0.f, 0.f, 0.f};
#pragma unroll
        for (int jc = 0; jc < 8; jc += 4) {
            bf16x8 kf[4][2];
#pragma unroll
            for (int j4 = 0; j4 < 4; ++j4)
#pragma unroll
                for (int kk = 0; kk < 2; ++kk)
                    kf[j4][kk] = *(const bf16x8*)&Kb[(long)(w * 128 + (jc + j4) * 16 + lr) * kHD + kk * 32 + lg * 8];
#pragma unroll
            for (int j4 = 0; j4 < 4; ++j4)
#pragma unroll
                for (int kk = 0; kk < 2; ++kk) {
                    acc[0][jc + j4] = __builtin_amdgcn_mfma_f32_16x16x32_bf16(af[0][kk], kf[j4][kk], acc[0][jc + j4], 0, 0, 0);
                    acc[1][jc + j4] = __builtin_amdgcn_mfma_f32_16x16x32_bf16(af[1][kk], kf[j4][kk], acc[1][jc + j4], 0, 0, 0);
                }
        }

        // row max (wave's 128 cols -> cross-wave via LDS)
#pragma unroll
        for (int i = 0; i < 2; ++i)
#pragma unroll
            for (int rr = 0; rr < 4; ++rr) {
                float m = acc[i][0][rr];
#pragma unroll
                for (int j = 1; j < 8; ++j) m = fmaxf(m, acc[i][j][rr]);
#pragma unroll
                for (int off = 1; off < 16; off <<= 1) m = fmaxf(m, __shfl_xor(m, off));
                if (lr == 0) redm[i * 16 + lg * 4 + rr][w] = m;
            }
        __syncthreads();   // (A) also protects Ps: all prior-b PV reads done
        float fm[2][4];
#pragma unroll
        for (int i = 0; i < 2; ++i)
#pragma unroll
            for (int rr = 0; rr < 4; ++rr) {
                const int row = i * 16 + lg * 4 + rr;
                float4 a = *(const float4*)&redm[row][0];
                float4 c = *(const float4*)&redm[row][4];
                fm[i][rr] = fmaxf(fmaxf(fmaxf(a.x, a.y), fmaxf(a.z, a.w)),
                                  fmaxf(fmaxf(c.x, c.y), fmaxf(c.z, c.w)));
            }
        // exp + row sum
#pragma unroll
        for (int i = 0; i < 2; ++i)
#pragma unroll
            for (int rr = 0; rr < 4; ++rr) {
                float s = 0.f;
#pragma unroll
                for (int j = 0; j < 8; ++j) {
                    float e = __expf((acc[i][j][rr] - fm[i][rr]) * scale);
                    acc[i][j][rr] = e;
                    s += e;
                }
#pragma unroll
                for (int off = 1; off < 16; off <<= 1) s += __shfl_xor(s, off);
                if (lr == 0) reds[i * 16 + lg * 4 + rr][w] = s;
            }
        __syncthreads();   // (B)

        float inv[2][4];
#pragma unroll
        for (int i = 0; i < 2; ++i)
#pragma unroll
            for (int rr = 0; rr < 4; ++rr) {
                const int row = i * 16 + lg * 4 + rr;
                float4 a = *(const float4*)&reds[row][0];
                float4 c = *(const float4*)&reds[row][4];
                inv[i][rr] = 1.f / ((a.x + a.y + a.z + a.w) + (c.x + c.y + c.z + c.w));
            }

        // normalized P -> Ps (16B-block XOR swizzle) + attm accumulate
#pragma unroll
        for (int i = 0; i < 2; ++i)
#pragma unroll
            for (int rr = 0; rr < 4; ++rr) {
                const int row = i * 16 + lg * 4 + rr;
                const float iv = inv[i][rr];
#pragma unroll
                for (int j = 0; j < 8; ++j) {
                    const int col = w * 128 + j * 16 + lr;
                    const float p = acc[i][j][rr] * iv;
                    am[i][j][rr] += p * 0.25f;
                    Ps[row * kT + (((col >> 3) ^ (row & 7)) << 3) + (col & 7)] = (bf16)p;
                }
            }
        __syncthreads();   // (C) Ps visible

        // PV: A from Ps (swizzled ds_read), B = VT rows direct from L2
        f32x4 yacc = (f32x4){0.f, 0.f, 0.f, 0.f};
        const int rowA = rh * 16 + lr;
        const long dRow = (long)(ch * 16 + lr) * kT;
#pragma unroll 4
        for (int kb = 0; kb < 32; ++kb) {
            const bf16x8 a = *(const bf16x8*)&Ps[rowA * kT + (((kb * 4 + lg) ^ (rowA & 7)) << 3)];
            const bf16x8 v = *(const bf16x8*)&Vb[dRow + kb * 32 + lg * 8];
            yacc = __builtin_amdgcn_mfma_f32_16x16x32_bf16(a, v, yacc, 0, 0, 0);
        }
#pragma unroll
        for (int rr = 0; rr < 4; ++rr)
            yg[((long)b * kT + q0 + rh * 16 + lg * 4 + rr) * kC + h * kHD + ch * 16 + lr] = (bf16)yacc[rr];
        // next-b Ps writes are after barrier (A)+(B) -> no extra barrier here
    }

    __syncthreads();   // all PV Ps reads done before fp32 reuse
    // attm write, coalesced via LDS: two 64KB halves of [32][512] fp32
    float* amf = (float*)Ps;
#pragma unroll
    for (int hf = 0; hf < 2; ++hf) {
        if ((w >> 2) == hf) {
            const int w2 = w & 3;
#pragma unroll
            for (int i = 0; i < 2; ++i)
#pragma unroll
                for (int rr = 0; rr < 4; ++rr) {
                    const int row = i * 16 + lg * 4 + rr;
#pragma unroll
                    for (int j = 0; j < 8; ++j)
                        amf[row * 512 + w2 * 128 + j * 16 + lr] = am[i][j][rr];
                }
        }
        __syncthreads();
#pragma unroll
        for (int p = 0; p < 8; ++p) {
            const int f = p * 512 + tid;            // 4096 float4s
            const int row = f >> 7, c4 = f & 127;
            float4 v = *(const float4*)&amf[row * 512 + c4 * 4];
            *(float4*)&attm[((long)h * kT + q0 + row) * kT + hf * 512 + c4 * 4] = v;
        }
        __syncthreads();
    }
}

__global__ __launch_bounds__(256)
void pool_kernel(const float* __restrict__ xf, float* __restrict__ pooled)
{
    const int c = blockIdx.x * 256 + threadIdx.x;
    const int b = blockIdx.y;
    const int t0 = blockIdx.z * 128;
    float s = 0.f;
    for (int t = t0; t < t0 + 128; ++t) s += xf[((long)b * kT + t) * kC + c];
    atomicAdd(&pooled[b * kC + c], s * (1.f / kT));
}

// ---------------------------------------------------------------------------
extern "C" void kernel_launch(void* const* d_in, const int* in_sizes, int n_in,
                              void* d_out, int out_size, void* d_ws, size_t ws_size,
                              hipStream_t stream)
{
    const int*   idx  = (const int*)d_in[0];
    const float* tok  = (const float*)d_in[1];
    const float* pos  = (const float*)d_in[2];
    const float* Wq   = (const float*)d_in[3];
    const float* bq   = (const float*)d_in[4];
    const float* Wk   = (const float*)d_in[5];
    const float* bk   = (const float*)d_in[6];
    const float* Wv   = (const float*)d_in[7];
    const float* bv   = (const float*)d_in[8];
    const float* Wo   = (const float*)d_in[9];
    const float* bo   = (const float*)d_in[10];
    const float* ln1w = (const float*)d_in[11];
    const float* ln1b = (const float*)d_in[12];
    const float* ln2w = (const float*)d_in[13];
    const float* ln2b = (const float*)d_in[14];
    const float* W1   = (const float*)d_in[15];
    const float* b1   = (const float*)d_in[16];
    const float* W2   = (const float*)d_in[17];
    const float* b2   = (const float*)d_in[18];
    const float* lnfw = (const float*)d_in[19];
    const float* lnfb = (const float*)d_in[20];

    char* ws = (char*)d_ws;
    long off = 0;
    auto alloc = [&](long bytes) { char* p = ws + off; off += (bytes + 255) & ~255L; return p; };
    bf16*  WQKVT = (bf16*)alloc((long)kL * 3 * kC * kC * 2);
    bf16*  WOT   = (bf16*)alloc((long)kL * kC * kC * 2);
    bf16*  W1T   = (bf16*)alloc((long)kL * kFFP * kC * 2);
    bf16*  W2T   = (bf16*)alloc((long)kL * kC * kFFP * 2);
    float* BQKV  = (float*)alloc((long)kL * 3 * kC * 4);
    float* X     = (float*)alloc((long)kM * kC * 4);
    bf16*  Hbuf  = (bf16*)alloc((long)kM * kC * 2);
    bf16*  QKV   = (bf16*)alloc(3L * kM * kC * 2);
    bf16*  Y     = (bf16*)alloc((long)kM * kC * 2);
    bf16*  F1    = (bf16*)alloc((long)kM * kFFP * 2);
    float* XF    = (float*)alloc((long)kM * kC * 4);

    float* pooled = (float*)d_out;
    float* attm_base = pooled + kB * kC;

    zero_kernel<<<16, 256, 0, stream>>>(pooled, kB * kC);
    dim3 tg(32, 32, kL);
    trans_cvt<<<tg, 256, 0, stream>>>(Wq, (long)kC * kC, WQKVT + 0L * kC * kC, 3L * kC * kC, kC, kC, kC, kC);
    trans_cvt<<<tg, 256, 0, stream>>>(Wk, (long)kC * kC, WQKVT + 1L * kC * kC, 3L * kC * kC, kC, kC, kC, kC);
    trans_cvt<<<tg, 256, 0, stream>>>(Wv, (long)kC * kC, WQKVT + 2L * kC * kC, 3L * kC * kC, kC, kC, kC, kC);
    trans_cvt<<<tg, 256, 0, stream>>>(Wo, (long)kC * kC, WOT, (long)kC * kC, kC, kC, kC, kC);
    trans_cvt<<<dim3(4, 32, kL), 256, 0, stream>>>(W1, (long)kC * kFF, W1T, (long)kFFP * kC, kC, kFF, kC, kFFP);
    trans_cvt<<<dim3(32, 4, kL), 256, 0, stream>>>(W2, (long)kFF * kC, W2T, (long)kC * kFFP, kFF, kC, kFFP, kC);
    pack_bias<<<48, 256, 0, stream>>>(bq, bk, bv, BQKV);

    embed_kernel<<<kM, 256, 0, stream>>>(idx, tok, pos, X);

    for (int l = 0; l < kL; ++l) {
        ln_kernel<<<kM, 256, 0, stream>>>(X, ln1w + l * kC, ln1b + l * kC, Hbuf, nullptr, 0);
        gemm_bf16<2, 2, 4, 4, 0, 1><<<dim3(8, 32, 3), 256, 0, stream>>>(
            Hbuf, 0L, WQKVT + (long)l * 3 * kC * kC, (long)kC * kC,
            BQKV + l * 3 * kC, kC, QKV, (long)kM * kC, nullptr,
            kC, kC, kC, kC);
        attn_fused<<<dim3(512), 512, 0, stream>>>(
            QKV, QKV + (long)kM * kC, QKV + 2L * kM * kC, Y,
            attm_base + (long)l * kH * kT * kT);
        gemm_bf16<2, 2, 4, 4, 4, 1><<<dim3(8, 32, 1), 256, 0, stream>>>(
            Y, 0L, WOT + (long)l * kC * kC, 0L, bo + l * kC, 0,
            nullptr, 0L, X, kC, kC, kC, kC);
        ln_kernel<<<kM, 256, 0, stream>>>(X, ln2w + l * kC, ln2b + l * kC, Hbuf, nullptr, 0);
        gemm_bf16<2, 2, 1, 2, 3, 0><<<dim3(2, 128, 1), 256, 0, stream>>>(
            Hbuf, 0L, W1T + (long)l * kFFP * kC, 0L, b1 + l * kFF, 0,
            F1, 0L, nullptr, kFFP, kC, kC, kC);
        gemm_bf16<2, 2, 4, 4, 4, 1><<<dim3(8, 32, 1), 256, 0, stream>>>(
            F1, 0L, W2T + (long)l * kC * kFFP, 0L, b2 + l * kC, 0,
            nullptr, 0L, X, kC, kFFP, kFFP, kFFP);
    }
    ln_kernel<<<kM, 256, 0, stream>>>(X, lnfw, lnfb, nullptr, XF, 1);
    pool_kernel<<<dim3(4, kB, 8), 256, 0, stream>>>(XF, pooled);
}